// Round 6
// baseline (10.574 us; speedup 1.0000x reference)
//
#include <hip/hip_runtime.h>
#include <stdint.h>

namespace {
constexpr int kH = 1024;
constexpr int kW = 2048;
constexpr int kNBX = kW / 256;  // 8 x-blocks
}

typedef int v4i __attribute__((ext_vector_type(4)));

__device__ __forceinline__ uint32_t pk2(int lo, int hi) {
    return (uint32_t)lo | ((uint32_t)hi << 16);  // labels 0..19, no masking
}
__device__ __forceinline__ uint32_t pkmin(uint32_t a, uint32_t b) {
    uint32_t d;
    asm("v_pk_min_i16 %0, %1, %2" : "=v"(d) : "v"(a), "v"(b));
    return d;
}
__device__ __forceinline__ uint32_t pkmax(uint32_t a, uint32_t b) {
    uint32_t d;
    asm("v_pk_max_i16 %0, %1, %2" : "=v"(d) : "v"(a), "v"(b));
    return d;
}
// pk2(lo.hi16, hi.lo16) -> v_alignbit_b32
__device__ __forceinline__ uint32_t algn(uint32_t hi, uint32_t lo) {
    return (lo >> 16) | (hi << 16);
}

// 4x2 output tile per thread, fully streaming: 6 input rows (y0-2..y0+3) are
// merged on the fly into 8 packed accumulators (4 per output row). Each row
// contributes to exactly one output at each radius:
//   out0: r2[j=2], r1[j=1], r1[j=3], center[j=0], center[j=4]
//   out1: r2[j=3], r1[j=2], r1[j=4], center[j=1], center[j=5]
// Horizontal halos from neighbor lanes (shfl + v_alignbit); block-edge halos
// from one predicated int2 load in lanes 0..5 / 8..13. Clamp-to-edge at image
// borders is neutral for a disk min/max stencil. No LDS, no barrier.
__global__ __launch_bounds__(256, 8) void boundary_edge_kernel(const int* __restrict__ lab,
                                                               int* __restrict__ out) {
    const int lane = threadIdx.x;  // one wave per threadIdx.y
    const int ty   = threadIdx.y;
    const int bx   = blockIdx.x;
    const int x0   = (bx * 64 + lane) * 4;
    const int y0   = (blockIdx.y * 4 + ty) * 2;
    const int bi   = blockIdx.z;
    const int* img = lab + (size_t)bi * kH * kW;

    const bool hasL = (bx > 0);
    const bool hasR = (bx < kNBX - 1);

    // One predicated 8B edge-halo load; lanes 0..5 left, 8..13 right (j = lane&7).
    uint32_t hv = 0;
    {
        const int j = lane & 7;
        const int ry = min(max(y0 + j - 2, 0), kH - 1);
        const bool doL = (lane < 8) && (j < 6) && hasL;
        const bool doR = (lane >= 8) && (lane < 16) && (j < 6) && hasR;
        if (doL | doR) {
            const int xh = (lane < 8) ? (bx * 256 - 2) : (bx * 256 + 256);
            const int2 t = *reinterpret_cast<const int2*>(img + (size_t)ry * kW + xh);
            hv = pk2(t.x, t.y);  // left: (m2,m1); right: (p4,p5)
        }
    }

    // Hoist all 6 row loads (independent addresses -> max MLP).
    int4 v[6];
#pragma unroll
    for (int j = 0; j < 6; ++j) {
        const int ry = min(max(y0 + j - 2, 0), kH - 1);  // clamp-to-edge
        v[j] = *reinterpret_cast<const int4*>(img + (size_t)ry * kW + x0);
    }

    // r1 (dx in [-1,1]) for one row; also returns Bl/Ar for the r2 extension.
    auto rowR1 = [&](int jj, const int4& vv, uint32_t& Bl, uint32_t& Ar,
                     uint32_t& mn01, uint32_t& mx01, uint32_t& mn23, uint32_t& mx23) {
        const uint32_t A = pk2(vv.x, vv.y);
        const uint32_t B = pk2(vv.z, vv.w);
        Bl = __shfl_up(B, 1);    // left lane's (v.z,v.w) = (m2,m1)
        Ar = __shfl_down(A, 1);  // right lane's (v.x,v.y) = (p4,p5)
        const uint32_t fL = hasL ? __shfl(hv, jj)     : pk2(vv.x, vv.x);
        const uint32_t fR = hasR ? __shfl(hv, jj + 8) : pk2(vv.w, vv.w);
        if (lane == 0)  Bl = fL;
        if (lane == 63) Ar = fR;
        const uint32_t L1 = algn(A, Bl);   // (m1, v.x)
        const uint32_t M  = algn(B, A);    // (v.y, v.z)
        const uint32_t N  = algn(Ar, B);   // (v.w, p4)
        mn01 = pkmin(pkmin(L1, A), M);
        mx01 = pkmax(pkmax(L1, A), M);
        mn23 = pkmin(pkmin(M, B), N);
        mx23 = pkmax(pkmax(M, B), N);
    };

    uint32_t o0mn01, o0mx01, o0mn23, o0mx23;
    uint32_t o1mn01, o1mx01, o1mn23, o1mx23;

    // j=0: center -> out0 (init)
    {
        const uint32_t A = pk2(v[0].x, v[0].y), B = pk2(v[0].z, v[0].w);
        o0mn01 = o0mx01 = A;
        o0mn23 = o0mx23 = B;
    }
    // j=1: r1 -> out0; center -> out1 (init)
    {
        uint32_t Bl, Ar, a, b, c, d;
        rowR1(1, v[1], Bl, Ar, a, b, c, d);
        o0mn01 = pkmin(o0mn01, a); o0mx01 = pkmax(o0mx01, b);
        o0mn23 = pkmin(o0mn23, c); o0mx23 = pkmax(o0mx23, d);
        const uint32_t A = pk2(v[1].x, v[1].y), B = pk2(v[1].z, v[1].w);
        o1mn01 = o1mx01 = A;
        o1mn23 = o1mx23 = B;
    }
    // j=2: r1 -> out1; r2 -> out0
    {
        uint32_t Bl, Ar, a, b, c, d;
        rowR1(2, v[2], Bl, Ar, a, b, c, d);
        o1mn01 = pkmin(o1mn01, a); o1mx01 = pkmax(o1mx01, b);
        o1mn23 = pkmin(o1mn23, c); o1mx23 = pkmax(o1mx23, d);
        const uint32_t A = pk2(v[2].x, v[2].y), B = pk2(v[2].z, v[2].w);
        o0mn01 = pkmin(o0mn01, pkmin(a, pkmin(Bl, B)));
        o0mx01 = pkmax(o0mx01, pkmax(b, pkmax(Bl, B)));
        o0mn23 = pkmin(o0mn23, pkmin(c, pkmin(A, Ar)));
        o0mx23 = pkmax(o0mx23, pkmax(d, pkmax(A, Ar)));
    }
    // j=3: r1 -> out0; r2 -> out1
    {
        uint32_t Bl, Ar, a, b, c, d;
        rowR1(3, v[3], Bl, Ar, a, b, c, d);
        o0mn01 = pkmin(o0mn01, a); o0mx01 = pkmax(o0mx01, b);
        o0mn23 = pkmin(o0mn23, c); o0mx23 = pkmax(o0mx23, d);
        const uint32_t A = pk2(v[3].x, v[3].y), B = pk2(v[3].z, v[3].w);
        o1mn01 = pkmin(o1mn01, pkmin(a, pkmin(Bl, B)));
        o1mx01 = pkmax(o1mx01, pkmax(b, pkmax(Bl, B)));
        o1mn23 = pkmin(o1mn23, pkmin(c, pkmin(A, Ar)));
        o1mx23 = pkmax(o1mx23, pkmax(d, pkmax(A, Ar)));
    }
    // j=4: r1 -> out1; center -> out0
    {
        uint32_t Bl, Ar, a, b, c, d;
        rowR1(4, v[4], Bl, Ar, a, b, c, d);
        o1mn01 = pkmin(o1mn01, a); o1mx01 = pkmax(o1mx01, b);
        o1mn23 = pkmin(o1mn23, c); o1mx23 = pkmax(o1mx23, d);
        const uint32_t A = pk2(v[4].x, v[4].y), B = pk2(v[4].z, v[4].w);
        o0mn01 = pkmin(o0mn01, A); o0mx01 = pkmax(o0mx01, A);
        o0mn23 = pkmin(o0mn23, B); o0mx23 = pkmax(o0mx23, B);
    }
    // j=5: center -> out1
    {
        const uint32_t A = pk2(v[5].x, v[5].y), B = pk2(v[5].z, v[5].w);
        o1mn01 = pkmin(o1mn01, A); o1mx01 = pkmax(o1mx01, A);
        o1mn23 = pkmin(o1mn23, B); o1mx23 = pkmax(o1mx23, B);
    }

    // x-border flags (x0 is 4-aligned -> only extreme tiles qualify)
    const bool xb0 = (x0 == 0);            // covers x=0,1 via per-pixel check below
    const bool xbN = (x0 == kW - 4);
    int xb[4];
    xb[0] = xb0;
    xb[1] = xb0;
    xb[2] = xbN;
    xb[3] = xbN;

    // out row 0
    {
        const int y = y0;
        const uint32_t yb = (y <= 1) | (y >= kH - 2);
        const uint32_t d01 = o0mn01 ^ o0mx01;
        const uint32_t d23 = o0mn23 ^ o0mx23;
        v4i r;
        r.x = ((o0mx01 & 0xFFFFu) != 0u && (((d01 & 0xFFFFu) != 0u) | yb | xb[0])) ? 1 : 0;
        r.y = ((o0mx01 >> 16)     != 0u && (((d01 >> 16)     != 0u) | yb | xb[1])) ? 1 : 0;
        r.z = ((o0mx23 & 0xFFFFu) != 0u && (((d23 & 0xFFFFu) != 0u) | yb | xb[2])) ? 1 : 0;
        r.w = ((o0mx23 >> 16)     != 0u && (((d23 >> 16)     != 0u) | yb | xb[3])) ? 1 : 0;
        __builtin_nontemporal_store(r,
            reinterpret_cast<v4i*>(out + ((size_t)(bi * kH + y) * kW + x0)));
    }
    // out row 1
    {
        const int y = y0 + 1;
        const uint32_t yb = (y <= 1) | (y >= kH - 2);
        const uint32_t d01 = o1mn01 ^ o1mx01;
        const uint32_t d23 = o1mn23 ^ o1mx23;
        v4i r;
        r.x = ((o1mx01 & 0xFFFFu) != 0u && (((d01 & 0xFFFFu) != 0u) | yb | xb[0])) ? 1 : 0;
        r.y = ((o1mx01 >> 16)     != 0u && (((d01 >> 16)     != 0u) | yb | xb[1])) ? 1 : 0;
        r.z = ((o1mx23 & 0xFFFFu) != 0u && (((d23 & 0xFFFFu) != 0u) | yb | xb[2])) ? 1 : 0;
        r.w = ((o1mx23 >> 16)     != 0u && (((d23 >> 16)     != 0u) | yb | xb[3])) ? 1 : 0;
        __builtin_nontemporal_store(r,
            reinterpret_cast<v4i*>(out + ((size_t)(bi * kH + y) * kW + x0)));
    }
}

extern "C" void kernel_launch(void* const* d_in, const int* in_sizes, int n_in,
                              void* d_out, int out_size, void* d_ws, size_t ws_size,
                              hipStream_t stream) {
    const int* lab = (const int*)d_in[0];
    int* out = (int*)d_out;
    dim3 block(64, 4, 1);
    dim3 grid(kW / 256, kH / 8, 2);  // (8, 128, 2) = 2048 blocks, 8/CU
    boundary_edge_kernel<<<grid, block, 0, stream>>>(lab, out);
}